// Round 13
// baseline (596.112 us; speedup 1.0000x reference)
//
#include <hip/hip_runtime.h>

#define NN 100000
#define EE 1600000
#define CAP 64       // bucket capacity per node
#define NBIN 196     // ceil(NN/512) bins (bin = dst>>9)
#define BINSZ 512    // nodes per bin
#define BINCAP 10400 // fixed per-bin pair capacity (mean 8192 + 24 sigma)
#define CHA 4096     // phase-A chunk (edges per block)
#define NCA 391      // ceil(EE/CHA)
#define GROWS 384    // rows per gemm block (16 waves x 24)
#define GGRID 261    // ceil(NN/GROWS)

// ---------------- DPP-based reductions (no DS ops) ----------------
template<int CTRL>
__device__ __forceinline__ float dppadd(float x){
    int y = __builtin_amdgcn_update_dpp(0, __float_as_int(x), CTRL, 0xF, 0xF, true);
    return x + __int_as_float(y);
}
template<int H>
__device__ __forceinline__ float head_reduce(float p){
    p = dppadd<0xB1>(p);    // quad_perm xor1
    p = dppadd<0x4E>(p);    // quad_perm xor2
    p = dppadd<0x141>(p);   // row_half_mirror
    p = dppadd<0x140>(p);   // row_mirror
    if constexpr (H == 1){
        p += __shfl_xor(p, 16);
        p += __shfl_xor(p, 32);
    }
    return p;
}
template<int H>
__device__ __forceinline__ float edge_logit(float xv, float xr_v, float att_v){
    float v = xv + xr_v;
    v = fmaxf(v, 0.2f * v);              // leaky_relu(0.2), 2 instrs
    return head_reduce<H>(v * att_v);
}

// ================= bucket build (fixed-capacity bins) =================

// phase A: partition edges by bin into pairs[] at fixed bin bases
__global__ __launch_bounds__(256) void k_A(
    const int* __restrict__ e0, const int* __restrict__ e1, const int* __restrict__ e2,
    int2* __restrict__ p0, int2* __restrict__ p1, int2* __restrict__ p2,
    int* __restrict__ tail)     // 3*NBIN counters, pre-zeroed
{
    __shared__ int shist[NBIN], lbase[NBIN], gbase[NBIN], cur[NBIN];
    __shared__ int sd[CHA], ss[CHA], spp[CHA];
    const int l = blockIdx.x / NCA, c = blockIdx.x % NCA;
    const int* ei = (l==0? e0 : l==1? e1 : e2);
    int2* pr = (l==0? p0 : l==1? p1 : p2);
    const int base = c*CHA, n = min(CHA, EE-base);
    const int tid = threadIdx.x;
    for (int i=tid;i<NBIN;i+=256) shist[i]=0;
    __syncthreads();
    for (int i=tid;i<n;i+=256) atomicAdd(&shist[ei[EE+base+i]>>9],1);
    __syncthreads();
    if (tid==0){ int acc=0; for (int i=0;i<NBIN;++i){ lbase[i]=acc; acc+=shist[i]; } }
    __syncthreads();
    if (tid<NBIN){ gbase[tid] = atomicAdd(&tail[l*NBIN+tid], shist[tid]); cur[tid]=lbase[tid]; }
    __syncthreads();
    for (int i=tid;i<n;i+=256){
        const int d = ei[EE+base+i], s = ei[base+i];
        const int bb = d>>9;
        const int r = atomicAdd(&cur[bb],1);
        const int off = gbase[bb] + (r - lbase[bb]);
        sd[r]=d; ss[r]=s;
        spp[r] = (off < BINCAP) ? (bb*BINCAP + off) : -1;
    }
    __syncthreads();
    for (int i=tid;i<n;i+=256){ const int p = spp[i]; if (p >= 0) pr[p] = make_int2(sd[i], ss[i]); }
}

// phase B: per-bin LDS buckets (self-loop pre-seeded), coalesced write-out
__global__ __launch_bounds__(256) void k_B(
    const int2* __restrict__ p0, const int2* __restrict__ p1, const int2* __restrict__ p2,
    const int* __restrict__ tail,
    int* __restrict__ c0, int* __restrict__ s0,
    int* __restrict__ c1, int* __restrict__ s1,
    int* __restrict__ c2, int* __restrict__ s2)
{
    __shared__ int cnt[BINSZ];
    __shared__ __align__(16) int sl[BINSZ*CAP];   // 128 KB
    const int l = blockIdx.x / NBIN, b = blockIdx.x % NBIN;
    const int2* pr = (l==0? p0 : l==1? p1 : p2) + (size_t)b*BINCAP;
    int* gc = (l==0? c0 : l==1? c1 : c2);
    int* gs = (l==0? s0 : l==1? s1 : s2);
    const int n0 = b*BINSZ;
    const int nn = min(BINSZ, NN - n0);
    const int tid = threadIdx.x;
    for (int i=tid;i<nn;i+=256){ cnt[i]=1; sl[i*CAP]= n0+i; }
    __syncthreads();
    const int ec = min(tail[l*NBIN+b], BINCAP);
    for (int i=tid;i<ec;i+=256){
        const int2 e = pr[i];
        const int nd = e.x - n0;
        const int p = atomicAdd(&cnt[nd],1);
        if (p < CAP) sl[nd*CAP+p] = e.y;
    }
    __syncthreads();
    for (int i=tid;i<nn;i+=256) gc[n0+i] = cnt[i];
    const int t4 = nn*(CAP/4);
    int4* gs4 = (int4*)(gs + (size_t)n0*CAP);
    const int4* sl4 = (const int4*)sl;
    for (int i=tid;i<t4;i+=256) gs4[i] = sl4[i];
}

// ================= compute kernels =================

// dual GEMM, 1024-thr blocks, split output cols across blockIdx.y.
// Block = 384 rows x 32 cols; wave = 24 rows (6 iters x 4); lane: c=lane&31, rh=lane>>5.
// sW (32 cols) staged once (one barrier); sxT wave-private (no per-iter barriers).
template<int CIN>
__global__ __launch_bounds__(1024) void k_gemm(
    const float* __restrict__ x,
    const float* __restrict__ Wl, const float* __restrict__ bl,
    const float* __restrict__ Wr, const float* __restrict__ br,
    float* __restrict__ xl, float* __restrict__ xr)
{
    __shared__ float2 sW[CIN * 32];        // sW[k*32+c] = {Wl[k][col], Wr[k][col]}
    __shared__ float  sxT[16][CIN * 4];    // per-wave slice: [k][row 0..3]
    const int tid = threadIdx.x;
    const int ch = blockIdx.y;             // col half
    for (int i = tid; i < CIN * 32; i += 1024){
        const int k = i >> 5, c = i & 31;
        sW[i] = make_float2(Wl[k*64 + ch*32 + c], Wr[k*64 + ch*32 + c]);
    }
    __syncthreads();                       // the ONLY block barrier

    const int wave = tid >> 6, lane = tid & 63;
    const int c = lane & 31, rh = lane >> 5;
    const int col = ch*32 + c;
    const float blv = bl[col], brv = br[col];
    float* sx_my = sxT[wave];
    const int wrow0 = blockIdx.x * GROWS + wave * 24;

    for (int iter = 0; iter < 6; ++iter){
        const int rbase = wrow0 + iter * 4;
        #pragma unroll
        for (int j = 0; j < 4; ++j){
            int rc = rbase + j; rc = rc < NN ? rc : NN - 1;
            const float* xp = x + (size_t)rc * CIN;
            #pragma unroll
            for (int k = lane; k < CIN; k += 64) sx_my[k * 4 + j] = xp[k];
        }
        float a0l = blv, a0r = brv, a1l = blv, a1r = brv;
        #pragma unroll 8
        for (int k = 0; k < CIN; ++k){
            const float2 w = sW[k * 32 + c];                              // bcast x2
            const float2 xv = *(const float2*)(sx_my + k * 4 + 2 * rh);   // bcast x2
            a0l = fmaf(xv.x, w.x, a0l); a0r = fmaf(xv.x, w.y, a0r);
            a1l = fmaf(xv.y, w.x, a1l); a1r = fmaf(xv.y, w.y, a1r);
        }
        const int r0 = rbase + 2 * rh;
        if (r0 < NN){ xl[(size_t)r0*64 + col] = a0l; xr[(size_t)r0*64 + col] = a0r; }
        if (r0 + 1 < NN){ xl[(size_t)(r0+1)*64 + col] = a1l; xr[(size_t)(r0+1)*64 + col] = a1r; }
    }
}

// fused per-node: 8-edge unrolled chunks, raw exp2/rcp/rsq, deferred-max softmax
template<int H, bool LAST>
__global__ __launch_bounds__(256) void k_fused(
    const int* __restrict__ cnt, const int* __restrict__ slots,
    const float* __restrict__ xl, const float* __restrict__ xr,
    const float* __restrict__ att, const float* __restrict__ bias,
    float* __restrict__ out)
{
    const int lane = threadIdx.x & 63;
    const int node = __builtin_amdgcn_readfirstlane(blockIdx.x * 4 + (threadIdx.x >> 6));
    if (node >= NN) return;
    const float xr_v = xr[(size_t)node*64 + lane];
    const float att_v = att[lane] * 1.44269504088896f;   // fold log2(e)
    int deg = __builtin_amdgcn_readfirstlane(cnt[node]);
    deg = deg > CAP ? CAP : deg;
    const int* __restrict__ sp = slots + (size_t)node * CAP;   // sp[0] = self

    const float xself = xl[(size_t)node*64 + lane];
    float m = edge_logit<H>(xself, xr_v, att_v);
    float den = 1.f, acc = xself;

    const int n = deg - 1;                 // non-self edges
    const int nchunk = (n + 7) >> 3;

    for (int c = 0; c < nchunk; ++c){
        const int b0 = 1 + c*8;
        const int nv = deg - b0;           // valid edges in this chunk (>=1)
        int id[8]; float xv[8], q[8], e[8];
        #pragma unroll
        for (int j = 0; j < 8; ++j) id[j] = (j < nv) ? sp[b0+j] : node;  // uniform selects
        #pragma unroll
        for (int j = 0; j < 8; ++j) xv[j] = xl[(size_t)id[j]*64 + lane];
        #pragma unroll
        for (int j = 0; j < 8; ++j) q[j] = edge_logit<H>(xv[j], xr_v, att_v);
        if (nv < 8){                        // tail chunk only: kill invalid edges
            #pragma unroll
            for (int j = 1; j < 8; ++j) if (j >= nv) q[j] = -16384.f;   // exp2 -> 0
        }
        const float pm = fmaxf(fmaxf(fmaxf(q[0],q[1]),fmaxf(q[2],q[3])),
                               fmaxf(fmaxf(q[4],q[5]),fmaxf(q[6],q[7])));
        if (__any(pm > m + 11.52f)){        // rare, exact rescale
            const float nm = fmaxf(m, pm);
            const float sc = __builtin_amdgcn_exp2f(m - nm);
            acc *= sc; den *= sc; m = nm;
        }
        #pragma unroll
        for (int j = 0; j < 8; ++j) e[j] = __builtin_amdgcn_exp2f(q[j] - m);
        #pragma unroll
        for (int j = 0; j < 8; ++j) acc = fmaf(e[j], xv[j], acc);
        den += ((e[0]+e[1]) + (e[2]+e[3])) + ((e[4]+e[5]) + (e[6]+e[7]));
    }

    float o = fmaf(acc, __builtin_amdgcn_rcpf(den + 1e-16f), bias[lane]);
    if (!LAST) o = fmaxf(o, 0.f);
    const float nsum = head_reduce<1>(fabsf(o));
    o *= __builtin_amdgcn_rcpf(fmaxf(nsum, 1e-12f));
    if (LAST){
        const float qq = head_reduce<1>(o * o);
        o *= __builtin_amdgcn_rsqf(fmaxf(qq, 1e-24f));
        o = fmaxf(o, 0.f);
    }
    out[(size_t)node*64 + lane] = o;
}

// ---- fallback-path build (atomic, R8 style) ----
__global__ __launch_bounds__(256) void k_init(int* __restrict__ cnt, int* __restrict__ slots)
{
    const int i = blockIdx.x * 256 + threadIdx.x;
    if (i < NN){ cnt[i] = 1; slots[(size_t)i * CAP] = i; }
}
__global__ __launch_bounds__(256) void k_build(
    const int* __restrict__ ei, int* __restrict__ cnt, int* __restrict__ slots)
{
    const int stride = gridDim.x * 256;
    for (int e = blockIdx.x * 256 + threadIdx.x; e < EE; e += stride){
        const int s = ei[e], d = ei[e + EE];
        const int pos = atomicAdd(&cnt[d], 1);
        if (pos < CAP) slots[(size_t)d * CAP + pos] = s;
    }
}

extern "C" void kernel_launch(void* const* d_in, const int* in_sizes, int n_in,
                              void* d_out, int out_size, void* d_ws, size_t ws_size,
                              hipStream_t stream)
{
    const float* x0 = (const float*)d_in[0];
    const int* ei[3] = {(const int*)d_in[1], (const int*)d_in[2], (const int*)d_in[3]};
    const float *Wl[3], *bl[3], *Wr[3], *br[3], *att[3], *bias[3];
    for (int i = 0; i < 3; ++i){
        Wl[i]   = (const float*)d_in[4 + 6*i];
        bl[i]   = (const float*)d_in[5 + 6*i];
        Wr[i]   = (const float*)d_in[6 + 6*i];
        br[i]   = (const float*)d_in[7 + 6*i];
        att[i]  = (const float*)d_in[8 + 6*i];
        bias[i] = (const float*)d_in[9 + 6*i];
    }
    float* out = (float*)d_out;

    const size_t NN64 = (size_t)NN * 64;
    float* xl = (float*)d_ws;
    float* xr = xl + NN64;
    float* xb = out;                        // inter-layer activation in d_out
    int* base = (int*)(xr + NN64);

    const size_t fused_need = (2*NN64 + 3*(size_t)NN*(CAP+1) + 3*NBIN) * 4;

    dim3 blk(256);
    dim3 gblk(1024);
    dim3 ggrid(GGRID, 2);
    const int ngrid = (NN + 3) / 4;
    const int igrid = (NN + 255) / 256;

    if (ws_size >= fused_need){
        // bucket arrays (3 layers)
        int* c0 = base;                 int* s0 = c0 + NN;
        int* c1 = s0 + (size_t)NN*CAP;  int* s1 = c1 + NN;
        int* c2 = s1 + (size_t)NN*CAP;  int* s2 = c2 + NN;
        int* tail = s2 + (size_t)NN*CAP;            // 3*NBIN ints
        // pairs buffers alias xl/xr (dead until gemm0 writes them): 48.9 MB <= 51.2 MB
        int2* p0 = (int2*)xl;
        int2* p1 = p0 + (size_t)NBIN*BINCAP;
        int2* p2 = p1 + (size_t)NBIN*BINCAP;

        hipMemsetAsync(tail, 0, 3*NBIN*sizeof(int), stream);
        k_A<<<3*NCA, blk, 0, stream>>>(ei[0], ei[1], ei[2], p0, p1, p2, tail);
        k_B<<<3*NBIN, blk, 0, stream>>>(p0, p1, p2, tail, c0, s0, c1, s1, c2, s2);

        k_gemm<128><<<ggrid, gblk, 0, stream>>>(x0, Wl[0], bl[0], Wr[0], br[0], xl, xr);
        k_fused<4,false><<<ngrid, blk, 0, stream>>>(c0, s0, xl, xr, att[0], bias[0], xb);
        k_gemm<64><<<ggrid, gblk, 0, stream>>>(xb, Wl[1], bl[1], Wr[1], br[1], xl, xr);
        k_fused<4,false><<<ngrid, blk, 0, stream>>>(c1, s1, xl, xr, att[1], bias[1], xb);
        k_gemm<64><<<ggrid, gblk, 0, stream>>>(xb, Wl[2], bl[2], Wr[2], br[2], xl, xr);
        k_fused<1,true><<<ngrid, blk, 0, stream>>>(c2, s2, xl, xr, att[2], bias[2], out);
    } else {
        // sequential fallback: one bucket set, atomic build
        int* cnt = base;
        int* slots = cnt + NN;

        k_init<<<igrid, blk, 0, stream>>>(cnt, slots);
        k_gemm<128><<<ggrid, gblk, 0, stream>>>(x0, Wl[0], bl[0], Wr[0], br[0], xl, xr);
        k_build<<<512, blk, 0, stream>>>(ei[0], cnt, slots);
        k_fused<4,false><<<ngrid, blk, 0, stream>>>(cnt, slots, xl, xr, att[0], bias[0], xb);

        k_init<<<igrid, blk, 0, stream>>>(cnt, slots);
        k_gemm<64><<<ggrid, gblk, 0, stream>>>(xb, Wl[1], bl[1], Wr[1], br[1], xl, xr);
        k_build<<<512, blk, 0, stream>>>(ei[1], cnt, slots);
        k_fused<4,false><<<ngrid, blk, 0, stream>>>(cnt, slots, xl, xr, att[1], bias[1], xb);

        k_init<<<igrid, blk, 0, stream>>>(cnt, slots);
        k_gemm<64><<<ggrid, gblk, 0, stream>>>(xb, Wl[2], bl[2], Wr[2], br[2], xl, xr);
        k_build<<<512, blk, 0, stream>>>(ei[2], cnt, slots);
        k_fused<1,true><<<ngrid, blk, 0, stream>>>(cnt, slots, xl, xr, att[2], bias[2], out);
    }
}

// Round 14
// 472.695 us; speedup vs baseline: 1.2611x; 1.2611x over previous
//
#include <hip/hip_runtime.h>
#include <hip/hip_fp16.h>

#define NN 100000
#define EE 1600000
#define CAP 64       // bucket capacity per node
#define NBIN 196     // ceil(NN/512) bins (bin = dst>>9)
#define BINSZ 512    // nodes per bin
#define BINCAP 10400 // fixed per-bin pair capacity (mean 8192 + 24 sigma)
#define CHA 4096     // phase-A chunk (edges per block)
#define NCA 391      // ceil(EE/CHA)

// ---------------- DPP-based reductions (no DS ops) ----------------
template<int CTRL>
__device__ __forceinline__ float dppadd(float x){
    int y = __builtin_amdgcn_update_dpp(0, __float_as_int(x), CTRL, 0xF, 0xF, true);
    return x + __int_as_float(y);
}
template<int H>
__device__ __forceinline__ float head_reduce(float p){
    p = dppadd<0xB1>(p);    // quad_perm xor1
    p = dppadd<0x4E>(p);    // quad_perm xor2
    p = dppadd<0x141>(p);   // row_half_mirror
    p = dppadd<0x140>(p);   // row_mirror
    if constexpr (H == 1){
        p += __shfl_xor(p, 16);
        p += __shfl_xor(p, 32);
    }
    return p;
}
template<int H>
__device__ __forceinline__ float edge_logit(float xv, float xr_v, float att_v){
    float v = xv + xr_v;
    v = fmaxf(v, 0.2f * v);              // leaky_relu(0.2), 2 instrs
    return head_reduce<H>(v * att_v);
}

// ================= bucket build (fixed-capacity bins) =================

// phase A: partition edges by bin into pairs[] at fixed bin bases
__global__ __launch_bounds__(256) void k_A(
    const int* __restrict__ e0, const int* __restrict__ e1, const int* __restrict__ e2,
    int2* __restrict__ p0, int2* __restrict__ p1, int2* __restrict__ p2,
    int* __restrict__ tail)     // 3*NBIN counters, pre-zeroed
{
    __shared__ int shist[NBIN], lbase[NBIN], gbase[NBIN], cur[NBIN];
    __shared__ int sd[CHA], ss[CHA], spp[CHA];
    const int l = blockIdx.x / NCA, c = blockIdx.x % NCA;
    const int* ei = (l==0? e0 : l==1? e1 : e2);
    int2* pr = (l==0? p0 : l==1? p1 : p2);
    const int base = c*CHA, n = min(CHA, EE-base);
    const int tid = threadIdx.x;
    for (int i=tid;i<NBIN;i+=256) shist[i]=0;
    __syncthreads();
    for (int i=tid;i<n;i+=256) atomicAdd(&shist[ei[EE+base+i]>>9],1);
    __syncthreads();
    if (tid==0){ int acc=0; for (int i=0;i<NBIN;++i){ lbase[i]=acc; acc+=shist[i]; } }
    __syncthreads();
    if (tid<NBIN){ gbase[tid] = atomicAdd(&tail[l*NBIN+tid], shist[tid]); cur[tid]=lbase[tid]; }
    __syncthreads();
    for (int i=tid;i<n;i+=256){
        const int d = ei[EE+base+i], s = ei[base+i];
        const int bb = d>>9;
        const int r = atomicAdd(&cur[bb],1);
        const int off = gbase[bb] + (r - lbase[bb]);
        sd[r]=d; ss[r]=s;
        spp[r] = (off < BINCAP) ? (bb*BINCAP + off) : -1;
    }
    __syncthreads();
    for (int i=tid;i<n;i+=256){ const int p = spp[i]; if (p >= 0) pr[p] = make_int2(sd[i], ss[i]); }
}

// phase B: per-bin LDS buckets (self-loop pre-seeded), coalesced write-out
__global__ __launch_bounds__(256) void k_B(
    const int2* __restrict__ p0, const int2* __restrict__ p1, const int2* __restrict__ p2,
    const int* __restrict__ tail,
    int* __restrict__ c0, int* __restrict__ s0,
    int* __restrict__ c1, int* __restrict__ s1,
    int* __restrict__ c2, int* __restrict__ s2)
{
    __shared__ int cnt[BINSZ];
    __shared__ __align__(16) int sl[BINSZ*CAP];   // 128 KB
    const int l = blockIdx.x / NBIN, b = blockIdx.x % NBIN;
    const int2* pr = (l==0? p0 : l==1? p1 : p2) + (size_t)b*BINCAP;
    int* gc = (l==0? c0 : l==1? c1 : c2);
    int* gs = (l==0? s0 : l==1? s1 : s2);
    const int n0 = b*BINSZ;
    const int nn = min(BINSZ, NN - n0);
    const int tid = threadIdx.x;
    for (int i=tid;i<nn;i+=256){ cnt[i]=1; sl[i*CAP]= n0+i; }
    __syncthreads();
    const int ec = min(tail[l*NBIN+b], BINCAP);
    for (int i=tid;i<ec;i+=256){
        const int2 e = pr[i];
        const int nd = e.x - n0;
        const int p = atomicAdd(&cnt[nd],1);
        if (p < CAP) sl[nd*CAP+p] = e.y;
    }
    __syncthreads();
    for (int i=tid;i<nn;i+=256) gc[n0+i] = cnt[i];
    const int t4 = nn*(CAP/4);
    int4* gs4 = (int4*)(gs + (size_t)n0*CAP);
    const int4* sl4 = (const int4*)sl;
    for (int i=tid;i<t4;i+=256) gs4[i] = sl4[i];
}

// ================= compute kernels =================

// dual GEMM: xl = x@Wl+bl, xr = x@Wr+br. W tile in LDS as fp16 pairs (32/16 KB),
// staged once (one barrier); sxT wave-private -> no per-iter barriers.
// fp16 W: rel err ~5e-4, well under output threshold.
template<int CIN>
__global__ __launch_bounds__(256) void k_gemm(
    const float* __restrict__ x,
    const float* __restrict__ Wl, const float* __restrict__ bl,
    const float* __restrict__ Wr, const float* __restrict__ br,
    float* __restrict__ xl, float* __restrict__ xr)
{
    __shared__ __half2 sW[CIN * 64];       // sW[k*64+c] = {Wl[k][c], Wr[k][c]} fp16
    __shared__ float  sxT[4][CIN * 4];     // per-wave slice: [k][row 0..3]
    const int tid = threadIdx.x;
    for (int i = tid; i < CIN * 64; i += 256)
        sW[i] = __floats2half2_rn(Wl[i], Wr[i]);
    __syncthreads();                       // the ONLY block barrier

    const int wave = tid >> 6, lane = tid & 63;
    const float blv = bl[lane], brv = br[lane];
    float* sx_my = sxT[wave];
    const float4* sx4 = (const float4*)sx_my;
    const int wrow0 = blockIdx.x * 64 + wave * 16;

    for (int iter = 0; iter < 4; ++iter){
        const int rbase = wrow0 + iter * 4;
        #pragma unroll
        for (int j = 0; j < 4; ++j){
            int rc = rbase + j; rc = rc < NN ? rc : NN - 1;
            const float* xp = x + (size_t)rc * CIN;
            #pragma unroll
            for (int k = lane; k < CIN; k += 64) sx_my[k * 4 + j] = xp[k];
        }
        float a0l = blv, a0r = brv, a1l = blv, a1r = brv;
        float a2l = blv, a2r = brv, a3l = blv, a3r = brv;
        #pragma unroll 8
        for (int k = 0; k < CIN; ++k){
            const __half2 w = sW[k * 64 + lane];
            const float wx = __low2float(w), wy = __high2float(w);
            const float4 xv = sx4[k];      // same addr across wave -> LDS broadcast
            a0l = fmaf(xv.x, wx, a0l); a0r = fmaf(xv.x, wy, a0r);
            a1l = fmaf(xv.y, wx, a1l); a1r = fmaf(xv.y, wy, a1r);
            a2l = fmaf(xv.z, wx, a2l); a2r = fmaf(xv.z, wy, a2r);
            a3l = fmaf(xv.w, wx, a3l); a3r = fmaf(xv.w, wy, a3r);
        }
        if (rbase + 0 < NN){ xl[(rbase+0)*64 + lane] = a0l; xr[(rbase+0)*64 + lane] = a0r; }
        if (rbase + 1 < NN){ xl[(rbase+1)*64 + lane] = a1l; xr[(rbase+1)*64 + lane] = a1r; }
        if (rbase + 2 < NN){ xl[(rbase+2)*64 + lane] = a2l; xr[(rbase+2)*64 + lane] = a2r; }
        if (rbase + 3 < NN){ xl[(rbase+3)*64 + lane] = a3l; xr[(rbase+3)*64 + lane] = a3r; }
    }
}

// fused per-node: 8-edge unrolled chunks, raw exp2/rcp/rsq, deferred-max softmax
template<int H, bool LAST>
__global__ __launch_bounds__(256) void k_fused(
    const int* __restrict__ cnt, const int* __restrict__ slots,
    const float* __restrict__ xl, const float* __restrict__ xr,
    const float* __restrict__ att, const float* __restrict__ bias,
    float* __restrict__ out)
{
    const int lane = threadIdx.x & 63;
    const int node = __builtin_amdgcn_readfirstlane(blockIdx.x * 4 + (threadIdx.x >> 6));
    if (node >= NN) return;
    const float xr_v = xr[(size_t)node*64 + lane];
    const float att_v = att[lane] * 1.44269504088896f;   // fold log2(e)
    int deg = __builtin_amdgcn_readfirstlane(cnt[node]);
    deg = deg > CAP ? CAP : deg;
    const int* __restrict__ sp = slots + (size_t)node * CAP;   // sp[0] = self

    const float xself = xl[(size_t)node*64 + lane];
    float m = edge_logit<H>(xself, xr_v, att_v);
    float den = 1.f, acc = xself;

    const int n = deg - 1;                 // non-self edges
    const int nchunk = (n + 7) >> 3;

    for (int c = 0; c < nchunk; ++c){
        const int b0 = 1 + c*8;
        const int nv = deg - b0;           // valid edges in this chunk (>=1)
        int id[8]; float xv[8], q[8], e[8];
        #pragma unroll
        for (int j = 0; j < 8; ++j) id[j] = (j < nv) ? sp[b0+j] : node;  // uniform selects
        #pragma unroll
        for (int j = 0; j < 8; ++j) xv[j] = xl[(size_t)id[j]*64 + lane];
        #pragma unroll
        for (int j = 0; j < 8; ++j) q[j] = edge_logit<H>(xv[j], xr_v, att_v);
        if (nv < 8){                        // tail chunk only: kill invalid edges
            #pragma unroll
            for (int j = 1; j < 8; ++j) if (j >= nv) q[j] = -16384.f;   // exp2 -> 0
        }
        const float pm = fmaxf(fmaxf(fmaxf(q[0],q[1]),fmaxf(q[2],q[3])),
                               fmaxf(fmaxf(q[4],q[5]),fmaxf(q[6],q[7])));
        if (__any(pm > m + 11.52f)){        // rare, exact rescale
            const float nm = fmaxf(m, pm);
            const float sc = __builtin_amdgcn_exp2f(m - nm);
            acc *= sc; den *= sc; m = nm;
        }
        #pragma unroll
        for (int j = 0; j < 8; ++j) e[j] = __builtin_amdgcn_exp2f(q[j] - m);
        #pragma unroll
        for (int j = 0; j < 8; ++j) acc = fmaf(e[j], xv[j], acc);
        den += ((e[0]+e[1]) + (e[2]+e[3])) + ((e[4]+e[5]) + (e[6]+e[7]));
    }

    float o = fmaf(acc, __builtin_amdgcn_rcpf(den + 1e-16f), bias[lane]);
    if (!LAST) o = fmaxf(o, 0.f);
    const float nsum = head_reduce<1>(fabsf(o));
    o *= __builtin_amdgcn_rcpf(fmaxf(nsum, 1e-12f));
    if (LAST){
        const float qq = head_reduce<1>(o * o);
        o *= __builtin_amdgcn_rsqf(fmaxf(qq, 1e-24f));
        o = fmaxf(o, 0.f);
    }
    out[(size_t)node*64 + lane] = o;
}

// ---- fallback-path build (atomic, R8 style) ----
__global__ __launch_bounds__(256) void k_init(int* __restrict__ cnt, int* __restrict__ slots)
{
    const int i = blockIdx.x * 256 + threadIdx.x;
    if (i < NN){ cnt[i] = 1; slots[(size_t)i * CAP] = i; }
}
__global__ __launch_bounds__(256) void k_build(
    const int* __restrict__ ei, int* __restrict__ cnt, int* __restrict__ slots)
{
    const int stride = gridDim.x * 256;
    for (int e = blockIdx.x * 256 + threadIdx.x; e < EE; e += stride){
        const int s = ei[e], d = ei[e + EE];
        const int pos = atomicAdd(&cnt[d], 1);
        if (pos < CAP) slots[(size_t)d * CAP + pos] = s;
    }
}

extern "C" void kernel_launch(void* const* d_in, const int* in_sizes, int n_in,
                              void* d_out, int out_size, void* d_ws, size_t ws_size,
                              hipStream_t stream)
{
    const float* x0 = (const float*)d_in[0];
    const int* ei[3] = {(const int*)d_in[1], (const int*)d_in[2], (const int*)d_in[3]};
    const float *Wl[3], *bl[3], *Wr[3], *br[3], *att[3], *bias[3];
    for (int i = 0; i < 3; ++i){
        Wl[i]   = (const float*)d_in[4 + 6*i];
        bl[i]   = (const float*)d_in[5 + 6*i];
        Wr[i]   = (const float*)d_in[6 + 6*i];
        br[i]   = (const float*)d_in[7 + 6*i];
        att[i]  = (const float*)d_in[8 + 6*i];
        bias[i] = (const float*)d_in[9 + 6*i];
    }
    float* out = (float*)d_out;

    const size_t NN64 = (size_t)NN * 64;
    float* xl = (float*)d_ws;
    float* xr = xl + NN64;
    float* xb = out;                        // inter-layer activation in d_out
    int* base = (int*)(xr + NN64);

    const size_t fused_need = (2*NN64 + 3*(size_t)NN*(CAP+1) + 3*NBIN) * 4;

    dim3 blk(256);
    const int ggrid = (NN + 63) / 64;
    const int ngrid = (NN + 3) / 4;
    const int igrid = (NN + 255) / 256;

    if (ws_size >= fused_need){
        // bucket arrays (3 layers)
        int* c0 = base;                 int* s0 = c0 + NN;
        int* c1 = s0 + (size_t)NN*CAP;  int* s1 = c1 + NN;
        int* c2 = s1 + (size_t)NN*CAP;  int* s2 = c2 + NN;
        int* tail = s2 + (size_t)NN*CAP;            // 3*NBIN ints
        // pairs buffers alias xl/xr (dead until gemm0 writes them): 48.9 MB <= 51.2 MB
        int2* p0 = (int2*)xl;
        int2* p1 = p0 + (size_t)NBIN*BINCAP;
        int2* p2 = p1 + (size_t)NBIN*BINCAP;

        hipMemsetAsync(tail, 0, 3*NBIN*sizeof(int), stream);
        k_A<<<3*NCA, blk, 0, stream>>>(ei[0], ei[1], ei[2], p0, p1, p2, tail);
        k_B<<<3*NBIN, blk, 0, stream>>>(p0, p1, p2, tail, c0, s0, c1, s1, c2, s2);

        k_gemm<128><<<ggrid, blk, 0, stream>>>(x0, Wl[0], bl[0], Wr[0], br[0], xl, xr);
        k_fused<4,false><<<ngrid, blk, 0, stream>>>(c0, s0, xl, xr, att[0], bias[0], xb);
        k_gemm<64><<<ggrid, blk, 0, stream>>>(xb, Wl[1], bl[1], Wr[1], br[1], xl, xr);
        k_fused<4,false><<<ngrid, blk, 0, stream>>>(c1, s1, xl, xr, att[1], bias[1], xb);
        k_gemm<64><<<ggrid, blk, 0, stream>>>(xb, Wl[2], bl[2], Wr[2], br[2], xl, xr);
        k_fused<1,true><<<ngrid, blk, 0, stream>>>(c2, s2, xl, xr, att[2], bias[2], out);
    } else {
        // sequential fallback: one bucket set, atomic build
        int* cnt = base;
        int* slots = cnt + NN;

        k_init<<<igrid, blk, 0, stream>>>(cnt, slots);
        k_gemm<128><<<ggrid, blk, 0, stream>>>(x0, Wl[0], bl[0], Wr[0], br[0], xl, xr);
        k_build<<<512, blk, 0, stream>>>(ei[0], cnt, slots);
        k_fused<4,false><<<ngrid, blk, 0, stream>>>(cnt, slots, xl, xr, att[0], bias[0], xb);

        k_init<<<igrid, blk, 0, stream>>>(cnt, slots);
        k_gemm<64><<<ggrid, blk, 0, stream>>>(xb, Wl[1], bl[1], Wr[1], br[1], xl, xr);
        k_build<<<512, blk, 0, stream>>>(ei[1], cnt, slots);
        k_fused<4,false><<<ngrid, blk, 0, stream>>>(cnt, slots, xl, xr, att[1], bias[1], xb);

        k_init<<<igrid, blk, 0, stream>>>(cnt, slots);
        k_gemm<64><<<ggrid, blk, 0, stream>>>(xb, Wl[2], bl[2], Wr[2], br[2], xl, xr);
        k_build<<<512, blk, 0, stream>>>(ei[2], cnt, slots);
        k_fused<1,true><<<ngrid, blk, 0, stream>>>(cnt, slots, xl, xr, att[2], bias[2], out);
    }
}

// Round 15
// 453.131 us; speedup vs baseline: 1.3155x; 1.0432x over previous
//
#include <hip/hip_runtime.h>
#include <hip/hip_fp16.h>

#define NN 100000
#define EE 1600000
#define CAP 64       // bucket capacity per node
#define NBIN 196     // ceil(NN/512) bins (bin = dst>>9)
#define BINSZ 512    // nodes per bin
#define BINCAP 10400 // fixed per-bin pair capacity (mean 8192 + 24 sigma)
#define CHA 4096     // phase-A chunk (edges per block)
#define NCA 391      // ceil(EE/CHA)

// ---------------- DPP-based reductions (no DS ops) ----------------
template<int CTRL>
__device__ __forceinline__ float dppadd(float x){
    int y = __builtin_amdgcn_update_dpp(0, __float_as_int(x), CTRL, 0xF, 0xF, true);
    return x + __int_as_float(y);
}
template<int H>
__device__ __forceinline__ float head_reduce(float p){
    p = dppadd<0xB1>(p);    // quad_perm xor1
    p = dppadd<0x4E>(p);    // quad_perm xor2
    p = dppadd<0x141>(p);   // row_half_mirror
    p = dppadd<0x140>(p);   // row_mirror
    if constexpr (H == 1){
        p += __shfl_xor(p, 16);
        p += __shfl_xor(p, 32);
    }
    return p;
}
template<int H>
__device__ __forceinline__ float edge_logit(float xv, float xr_v, float att_v){
    float v = xv + xr_v;
    v = fmaxf(v, 0.2f * v);              // leaky_relu(0.2), 2 instrs
    return head_reduce<H>(v * att_v);
}

// ================= bucket build (fixed-capacity bins) =================

// phase A: partition edges by bin into pairs[] at fixed bin bases
__global__ __launch_bounds__(256) void k_A(
    const int* __restrict__ e0, const int* __restrict__ e1, const int* __restrict__ e2,
    int2* __restrict__ p0, int2* __restrict__ p1, int2* __restrict__ p2,
    int* __restrict__ tail)     // 3*NBIN counters, pre-zeroed
{
    __shared__ int shist[NBIN], lbase[NBIN], gbase[NBIN], cur[NBIN];
    __shared__ int sd[CHA], ss[CHA], spp[CHA];
    const int l = blockIdx.x / NCA, c = blockIdx.x % NCA;
    const int* ei = (l==0? e0 : l==1? e1 : e2);
    int2* pr = (l==0? p0 : l==1? p1 : p2);
    const int base = c*CHA, n = min(CHA, EE-base);
    const int tid = threadIdx.x;
    for (int i=tid;i<NBIN;i+=256) shist[i]=0;
    __syncthreads();
    for (int i=tid;i<n;i+=256) atomicAdd(&shist[ei[EE+base+i]>>9],1);
    __syncthreads();
    if (tid==0){ int acc=0; for (int i=0;i<NBIN;++i){ lbase[i]=acc; acc+=shist[i]; } }
    __syncthreads();
    if (tid<NBIN){ gbase[tid] = atomicAdd(&tail[l*NBIN+tid], shist[tid]); cur[tid]=lbase[tid]; }
    __syncthreads();
    for (int i=tid;i<n;i+=256){
        const int d = ei[EE+base+i], s = ei[base+i];
        const int bb = d>>9;
        const int r = atomicAdd(&cur[bb],1);
        const int off = gbase[bb] + (r - lbase[bb]);
        sd[r]=d; ss[r]=s;
        spp[r] = (off < BINCAP) ? (bb*BINCAP + off) : -1;
    }
    __syncthreads();
    for (int i=tid;i<n;i+=256){ const int p = spp[i]; if (p >= 0) pr[p] = make_int2(sd[i], ss[i]); }
}

// phase B: per-bin LDS buckets (self-loop pre-seeded), coalesced write-out
__global__ __launch_bounds__(256) void k_B(
    const int2* __restrict__ p0, const int2* __restrict__ p1, const int2* __restrict__ p2,
    const int* __restrict__ tail,
    int* __restrict__ c0, int* __restrict__ s0,
    int* __restrict__ c1, int* __restrict__ s1,
    int* __restrict__ c2, int* __restrict__ s2)
{
    __shared__ int cnt[BINSZ];
    __shared__ __align__(16) int sl[BINSZ*CAP];   // 128 KB
    const int l = blockIdx.x / NBIN, b = blockIdx.x % NBIN;
    const int2* pr = (l==0? p0 : l==1? p1 : p2) + (size_t)b*BINCAP;
    int* gc = (l==0? c0 : l==1? c1 : c2);
    int* gs = (l==0? s0 : l==1? s1 : s2);
    const int n0 = b*BINSZ;
    const int nn = min(BINSZ, NN - n0);
    const int tid = threadIdx.x;
    for (int i=tid;i<nn;i+=256){ cnt[i]=1; sl[i*CAP]= n0+i; }
    __syncthreads();
    const int ec = min(tail[l*NBIN+b], BINCAP);
    for (int i=tid;i<ec;i+=256){
        const int2 e = pr[i];
        const int nd = e.x - n0;
        const int p = atomicAdd(&cnt[nd],1);
        if (p < CAP) sl[nd*CAP+p] = e.y;
    }
    __syncthreads();
    for (int i=tid;i<nn;i+=256) gc[n0+i] = cnt[i];
    const int t4 = nn*(CAP/4);
    int4* gs4 = (int4*)(gs + (size_t)n0*CAP);
    const int4* sl4 = (const int4*)sl;
    for (int i=tid;i<t4;i+=256) gs4[i] = sl4[i];
}

// ================= compute kernels =================

// dual GEMM: xl = x@Wl+bl, xr = x@Wr+br. W tile in LDS as fp16 pairs (32/16 KB),
// staged once (one barrier); sxT wave-private -> no per-iter barriers.
template<int CIN>
__global__ __launch_bounds__(256) void k_gemm(
    const float* __restrict__ x,
    const float* __restrict__ Wl, const float* __restrict__ bl,
    const float* __restrict__ Wr, const float* __restrict__ br,
    float* __restrict__ xl, float* __restrict__ xr)
{
    __shared__ __half2 sW[CIN * 64];       // sW[k*64+c] = {Wl[k][c], Wr[k][c]} fp16
    __shared__ float  sxT[4][CIN * 4];     // per-wave slice: [k][row 0..3]
    const int tid = threadIdx.x;
    for (int i = tid; i < CIN * 64; i += 256)
        sW[i] = __floats2half2_rn(Wl[i], Wr[i]);
    __syncthreads();                       // the ONLY block barrier

    const int wave = tid >> 6, lane = tid & 63;
    const float blv = bl[lane], brv = br[lane];
    float* sx_my = sxT[wave];
    const float4* sx4 = (const float4*)sx_my;
    const int wrow0 = blockIdx.x * 64 + wave * 16;

    for (int iter = 0; iter < 4; ++iter){
        const int rbase = wrow0 + iter * 4;
        #pragma unroll
        for (int j = 0; j < 4; ++j){
            int rc = rbase + j; rc = rc < NN ? rc : NN - 1;
            const float* xp = x + (size_t)rc * CIN;
            #pragma unroll
            for (int k = lane; k < CIN; k += 64) sx_my[k * 4 + j] = xp[k];
        }
        float a0l = blv, a0r = brv, a1l = blv, a1r = brv;
        float a2l = blv, a2r = brv, a3l = blv, a3r = brv;
        #pragma unroll 8
        for (int k = 0; k < CIN; ++k){
            const __half2 w = sW[k * 64 + lane];
            const float wx = __low2float(w), wy = __high2float(w);
            const float4 xv = sx4[k];      // same addr across wave -> LDS broadcast
            a0l = fmaf(xv.x, wx, a0l); a0r = fmaf(xv.x, wy, a0r);
            a1l = fmaf(xv.y, wx, a1l); a1r = fmaf(xv.y, wy, a1r);
            a2l = fmaf(xv.z, wx, a2l); a2r = fmaf(xv.z, wy, a2r);
            a3l = fmaf(xv.w, wx, a3l); a3r = fmaf(xv.w, wy, a3r);
        }
        if (rbase + 0 < NN){ xl[(rbase+0)*64 + lane] = a0l; xr[(rbase+0)*64 + lane] = a0r; }
        if (rbase + 1 < NN){ xl[(rbase+1)*64 + lane] = a1l; xr[(rbase+1)*64 + lane] = a1r; }
        if (rbase + 2 < NN){ xl[(rbase+2)*64 + lane] = a2l; xr[(rbase+2)*64 + lane] = a2r; }
        if (rbase + 3 < NN){ xl[(rbase+3)*64 + lane] = a3l; xr[(rbase+3)*64 + lane] = a3r; }
    }
}

// fused per-node: NO max subtraction (logits bounded |q| << 125 -> exp2 exact-ratio),
// self edge folded into chunk loop (sp[0]=self), scalar-forced slot ids.
template<int H, bool LAST>
__global__ __launch_bounds__(256) void k_fused(
    const int* __restrict__ cnt, const int* __restrict__ slots,
    const float* __restrict__ xl, const float* __restrict__ xr,
    const float* __restrict__ att, const float* __restrict__ bias,
    float* __restrict__ out)
{
    const int lane = threadIdx.x & 63;
    const int node = __builtin_amdgcn_readfirstlane(blockIdx.x * 4 + (threadIdx.x >> 6));
    if (node >= NN) return;
    const float xr_v = xr[(size_t)node*64 + lane];
    const float att_v = att[lane] * 1.44269504088896f;   // fold log2(e)
    const float bias_v = bias[lane];
    int deg = __builtin_amdgcn_readfirstlane(cnt[node]);
    deg = deg > CAP ? CAP : deg;
    const int* __restrict__ sp = slots + (size_t)node * CAP;   // sp[0] = self

    float den = 0.f, acc = 0.f;
    const int nchunk = (deg + 7) >> 3;

    for (int c = 0; c < nchunk; ++c){
        const int b0 = c*8;
        const int nv = deg - b0;           // valid edges in this chunk (>=1)
        int id[8]; float xv[8], q[8], e[8];
        #pragma unroll
        for (int j = 0; j < 8; ++j)
            id[j] = __builtin_amdgcn_readfirstlane((j < nv) ? sp[b0+j] : node);
        #pragma unroll
        for (int j = 0; j < 8; ++j) xv[j] = xl[(unsigned)(id[j]*64) + lane];
        #pragma unroll
        for (int j = 0; j < 8; ++j) q[j] = edge_logit<H>(xv[j], xr_v, att_v);
        if (nv < 8){                        // tail chunk only: kill invalid edges
            #pragma unroll
            for (int j = 1; j < 8; ++j) if (j >= nv) q[j] = -16384.f;   // exp2 -> 0
        }
        #pragma unroll
        for (int j = 0; j < 8; ++j) e[j] = __builtin_amdgcn_exp2f(q[j]);
        #pragma unroll
        for (int j = 0; j < 8; ++j) acc = fmaf(e[j], xv[j], acc);
        den += ((e[0]+e[1]) + (e[2]+e[3])) + ((e[4]+e[5]) + (e[6]+e[7]));
    }

    float o = fmaf(acc, __builtin_amdgcn_rcpf(den), bias_v);
    if (!LAST) o = fmaxf(o, 0.f);
    const float nsum = head_reduce<1>(fabsf(o));
    o *= __builtin_amdgcn_rcpf(fmaxf(nsum, 1e-12f));
    if (LAST){
        const float qq = head_reduce<1>(o * o);
        o *= __builtin_amdgcn_rsqf(fmaxf(qq, 1e-24f));
        o = fmaxf(o, 0.f);
    }
    out[(size_t)node*64 + lane] = o;
}

// ---- fallback-path build (atomic, R8 style) ----
__global__ __launch_bounds__(256) void k_init(int* __restrict__ cnt, int* __restrict__ slots)
{
    const int i = blockIdx.x * 256 + threadIdx.x;
    if (i < NN){ cnt[i] = 1; slots[(size_t)i * CAP] = i; }
}
__global__ __launch_bounds__(256) void k_build(
    const int* __restrict__ ei, int* __restrict__ cnt, int* __restrict__ slots)
{
    const int stride = gridDim.x * 256;
    for (int e = blockIdx.x * 256 + threadIdx.x; e < EE; e += stride){
        const int s = ei[e], d = ei[e + EE];
        const int pos = atomicAdd(&cnt[d], 1);
        if (pos < CAP) slots[(size_t)d * CAP + pos] = s;
    }
}

extern "C" void kernel_launch(void* const* d_in, const int* in_sizes, int n_in,
                              void* d_out, int out_size, void* d_ws, size_t ws_size,
                              hipStream_t stream)
{
    const float* x0 = (const float*)d_in[0];
    const int* ei[3] = {(const int*)d_in[1], (const int*)d_in[2], (const int*)d_in[3]};
    const float *Wl[3], *bl[3], *Wr[3], *br[3], *att[3], *bias[3];
    for (int i = 0; i < 3; ++i){
        Wl[i]   = (const float*)d_in[4 + 6*i];
        bl[i]   = (const float*)d_in[5 + 6*i];
        Wr[i]   = (const float*)d_in[6 + 6*i];
        br[i]   = (const float*)d_in[7 + 6*i];
        att[i]  = (const float*)d_in[8 + 6*i];
        bias[i] = (const float*)d_in[9 + 6*i];
    }
    float* out = (float*)d_out;

    const size_t NN64 = (size_t)NN * 64;
    float* xl = (float*)d_ws;
    float* xr = xl + NN64;
    float* xb = out;                        // inter-layer activation in d_out
    int* base = (int*)(xr + NN64);

    const size_t fused_need = (2*NN64 + 3*(size_t)NN*(CAP+1) + 3*NBIN) * 4;

    dim3 blk(256);
    const int ggrid = (NN + 63) / 64;
    const int ngrid = (NN + 3) / 4;
    const int igrid = (NN + 255) / 256;

    if (ws_size >= fused_need){
        // bucket arrays (3 layers)
        int* c0 = base;                 int* s0 = c0 + NN;
        int* c1 = s0 + (size_t)NN*CAP;  int* s1 = c1 + NN;
        int* c2 = s1 + (size_t)NN*CAP;  int* s2 = c2 + NN;
        int* tail = s2 + (size_t)NN*CAP;            // 3*NBIN ints
        // pairs buffers alias xl/xr (dead until gemm0 writes them): 48.9 MB <= 51.2 MB
        int2* p0 = (int2*)xl;
        int2* p1 = p0 + (size_t)NBIN*BINCAP;
        int2* p2 = p1 + (size_t)NBIN*BINCAP;

        hipMemsetAsync(tail, 0, 3*NBIN*sizeof(int), stream);
        k_A<<<3*NCA, blk, 0, stream>>>(ei[0], ei[1], ei[2], p0, p1, p2, tail);
        k_B<<<3*NBIN, blk, 0, stream>>>(p0, p1, p2, tail, c0, s0, c1, s1, c2, s2);

        k_gemm<128><<<ggrid, blk, 0, stream>>>(x0, Wl[0], bl[0], Wr[0], br[0], xl, xr);
        k_fused<4,false><<<ngrid, blk, 0, stream>>>(c0, s0, xl, xr, att[0], bias[0], xb);
        k_gemm<64><<<ggrid, blk, 0, stream>>>(xb, Wl[1], bl[1], Wr[1], br[1], xl, xr);
        k_fused<4,false><<<ngrid, blk, 0, stream>>>(c1, s1, xl, xr, att[1], bias[1], xb);
        k_gemm<64><<<ggrid, blk, 0, stream>>>(xb, Wl[2], bl[2], Wr[2], br[2], xl, xr);
        k_fused<1,true><<<ngrid, blk, 0, stream>>>(c2, s2, xl, xr, att[2], bias[2], out);
    } else {
        // sequential fallback: one bucket set, atomic build
        int* cnt = base;
        int* slots = cnt + NN;

        k_init<<<igrid, blk, 0, stream>>>(cnt, slots);
        k_gemm<128><<<ggrid, blk, 0, stream>>>(x0, Wl[0], bl[0], Wr[0], br[0], xl, xr);
        k_build<<<512, blk, 0, stream>>>(ei[0], cnt, slots);
        k_fused<4,false><<<ngrid, blk, 0, stream>>>(cnt, slots, xl, xr, att[0], bias[0], xb);

        k_init<<<igrid, blk, 0, stream>>>(cnt, slots);
        k_gemm<64><<<ggrid, blk, 0, stream>>>(xb, Wl[1], bl[1], Wr[1], br[1], xl, xr);
        k_build<<<512, blk, 0, stream>>>(ei[1], cnt, slots);
        k_fused<4,false><<<ngrid, blk, 0, stream>>>(cnt, slots, xl, xr, att[1], bias[1], xb);

        k_init<<<igrid, blk, 0, stream>>>(cnt, slots);
        k_gemm<64><<<ggrid, blk, 0, stream>>>(xb, Wl[2], bl[2], Wr[2], br[2], xl, xr);
        k_build<<<512, blk, 0, stream>>>(ei[2], cnt, slots);
        k_fused<1,true><<<ngrid, blk, 0, stream>>>(cnt, slots, xl, xr, att[2], bias[2], out);
    }
}

// Round 16
// 441.913 us; speedup vs baseline: 1.3489x; 1.0254x over previous
//
#include <hip/hip_runtime.h>
#include <hip/hip_fp16.h>

#define NN 100000
#define EE 1600000
#define CAP 64       // bucket capacity per node
#define NBIN 196     // ceil(NN/512) bins (bin = dst>>9)
#define BINSZ 512    // nodes per bin
#define BINCAP 10400 // fixed per-bin pair capacity (mean 8192 + 24 sigma)
#define CHA 4096     // phase-A chunk (edges per block)
#define NCA 391      // ceil(EE/CHA)

// ---------------- DPP-based reductions (no DS ops) ----------------
template<int CTRL>
__device__ __forceinline__ float dppadd(float x){
    int y = __builtin_amdgcn_update_dpp(0, __float_as_int(x), CTRL, 0xF, 0xF, true);
    return x + __int_as_float(y);
}
template<int H>
__device__ __forceinline__ float head_reduce(float p){
    p = dppadd<0xB1>(p);    // quad_perm xor1
    p = dppadd<0x4E>(p);    // quad_perm xor2
    p = dppadd<0x141>(p);   // row_half_mirror
    p = dppadd<0x140>(p);   // row_mirror
    if constexpr (H == 1){
        p += __shfl_xor(p, 16);
        p += __shfl_xor(p, 32);
    }
    return p;
}
template<int H>
__device__ __forceinline__ float edge_logit(float xv, float xr_v, float att_v){
    float v = xv + xr_v;
    v = fmaxf(v, 0.2f * v);              // leaky_relu(0.2), 2 instrs
    return head_reduce<H>(v * att_v);
}

// ================= bucket build (fixed-capacity bins) =================

// phase A: partition edges by bin into pairs[] at fixed bin bases
__global__ __launch_bounds__(256) void k_A(
    const int* __restrict__ e0, const int* __restrict__ e1, const int* __restrict__ e2,
    int2* __restrict__ p0, int2* __restrict__ p1, int2* __restrict__ p2,
    int* __restrict__ tail)     // 3*NBIN counters, pre-zeroed
{
    __shared__ int shist[NBIN], lbase[NBIN], gbase[NBIN], cur[NBIN];
    __shared__ int sd[CHA], ss[CHA], spp[CHA];
    const int l = blockIdx.x / NCA, c = blockIdx.x % NCA;
    const int* ei = (l==0? e0 : l==1? e1 : e2);
    int2* pr = (l==0? p0 : l==1? p1 : p2);
    const int base = c*CHA, n = min(CHA, EE-base);
    const int tid = threadIdx.x;
    for (int i=tid;i<NBIN;i+=256) shist[i]=0;
    __syncthreads();
    for (int i=tid;i<n;i+=256) atomicAdd(&shist[ei[EE+base+i]>>9],1);
    __syncthreads();
    if (tid==0){ int acc=0; for (int i=0;i<NBIN;++i){ lbase[i]=acc; acc+=shist[i]; } }
    __syncthreads();
    if (tid<NBIN){ gbase[tid] = atomicAdd(&tail[l*NBIN+tid], shist[tid]); cur[tid]=lbase[tid]; }
    __syncthreads();
    for (int i=tid;i<n;i+=256){
        const int d = ei[EE+base+i], s = ei[base+i];
        const int bb = d>>9;
        const int r = atomicAdd(&cur[bb],1);
        const int off = gbase[bb] + (r - lbase[bb]);
        sd[r]=d; ss[r]=s;
        spp[r] = (off < BINCAP) ? (bb*BINCAP + off) : -1;
    }
    __syncthreads();
    for (int i=tid;i<n;i+=256){ const int p = spp[i]; if (p >= 0) pr[p] = make_int2(sd[i], ss[i]); }
}

// phase B: per-bin LDS buckets (self-loop pre-seeded), coalesced write-out
__global__ __launch_bounds__(256) void k_B(
    const int2* __restrict__ p0, const int2* __restrict__ p1, const int2* __restrict__ p2,
    const int* __restrict__ tail,
    int* __restrict__ c0, int* __restrict__ s0,
    int* __restrict__ c1, int* __restrict__ s1,
    int* __restrict__ c2, int* __restrict__ s2)
{
    __shared__ int cnt[BINSZ];
    __shared__ __align__(16) int sl[BINSZ*CAP];   // 128 KB
    const int l = blockIdx.x / NBIN, b = blockIdx.x % NBIN;
    const int2* pr = (l==0? p0 : l==1? p1 : p2) + (size_t)b*BINCAP;
    int* gc = (l==0? c0 : l==1? c1 : c2);
    int* gs = (l==0? s0 : l==1? s1 : s2);
    const int n0 = b*BINSZ;
    const int nn = min(BINSZ, NN - n0);
    const int tid = threadIdx.x;
    for (int i=tid;i<nn;i+=256){ cnt[i]=1; sl[i*CAP]= n0+i; }
    __syncthreads();
    const int ec = min(tail[l*NBIN+b], BINCAP);
    for (int i=tid;i<ec;i+=256){
        const int2 e = pr[i];
        const int nd = e.x - n0;
        const int p = atomicAdd(&cnt[nd],1);
        if (p < CAP) sl[nd*CAP+p] = e.y;
    }
    __syncthreads();
    for (int i=tid;i<nn;i+=256) gc[n0+i] = cnt[i];
    const int t4 = nn*(CAP/4);
    int4* gs4 = (int4*)(gs + (size_t)n0*CAP);
    const int4* sl4 = (const int4*)sl;
    for (int i=tid;i<t4;i+=256) gs4[i] = sl4[i];
}

// ================= compute kernels =================

// dual GEMM: xl(fp16) = x@Wl+bl, xr(fp32) = x@Wr+br. W tile in LDS as fp16 pairs,
// staged once (one barrier); sxT wave-private -> no per-iter barriers.
template<int CIN>
__global__ __launch_bounds__(256) void k_gemm(
    const float* __restrict__ x,
    const float* __restrict__ Wl, const float* __restrict__ bl,
    const float* __restrict__ Wr, const float* __restrict__ br,
    __half* __restrict__ xlh, float* __restrict__ xr)
{
    __shared__ __half2 sW[CIN * 64];       // sW[k*64+c] = {Wl[k][c], Wr[k][c]} fp16
    __shared__ float  sxT[4][CIN * 4];     // per-wave slice: [k][row 0..3]
    const int tid = threadIdx.x;
    for (int i = tid; i < CIN * 64; i += 256)
        sW[i] = __floats2half2_rn(Wl[i], Wr[i]);
    __syncthreads();                       // the ONLY block barrier

    const int wave = tid >> 6, lane = tid & 63;
    const float blv = bl[lane], brv = br[lane];
    float* sx_my = sxT[wave];
    const float4* sx4 = (const float4*)sx_my;
    const int wrow0 = blockIdx.x * 64 + wave * 16;

    for (int iter = 0; iter < 4; ++iter){
        const int rbase = wrow0 + iter * 4;
        #pragma unroll
        for (int j = 0; j < 4; ++j){
            int rc = rbase + j; rc = rc < NN ? rc : NN - 1;
            const float* xp = x + (size_t)rc * CIN;
            #pragma unroll
            for (int k = lane; k < CIN; k += 64) sx_my[k * 4 + j] = xp[k];
        }
        float a0l = blv, a0r = brv, a1l = blv, a1r = brv;
        float a2l = blv, a2r = brv, a3l = blv, a3r = brv;
        #pragma unroll 8
        for (int k = 0; k < CIN; ++k){
            const __half2 w = sW[k * 64 + lane];
            const float wx = __low2float(w), wy = __high2float(w);
            const float4 xv = sx4[k];      // same addr across wave -> LDS broadcast
            a0l = fmaf(xv.x, wx, a0l); a0r = fmaf(xv.x, wy, a0r);
            a1l = fmaf(xv.y, wx, a1l); a1r = fmaf(xv.y, wy, a1r);
            a2l = fmaf(xv.z, wx, a2l); a2r = fmaf(xv.z, wy, a2r);
            a3l = fmaf(xv.w, wx, a3l); a3r = fmaf(xv.w, wy, a3r);
        }
        if (rbase + 0 < NN){ xlh[(size_t)(rbase+0)*64 + lane] = __float2half_rn(a0l); xr[(size_t)(rbase+0)*64 + lane] = a0r; }
        if (rbase + 1 < NN){ xlh[(size_t)(rbase+1)*64 + lane] = __float2half_rn(a1l); xr[(size_t)(rbase+1)*64 + lane] = a1r; }
        if (rbase + 2 < NN){ xlh[(size_t)(rbase+2)*64 + lane] = __float2half_rn(a2l); xr[(size_t)(rbase+2)*64 + lane] = a2r; }
        if (rbase + 3 < NN){ xlh[(size_t)(rbase+3)*64 + lane] = __float2half_rn(a3l); xr[(size_t)(rbase+3)*64 + lane] = a3r; }
    }
}

// fused per-node: fp16 xl gathers (128 B/edge), no max subtraction, self edge in
// chunk loop (sp[0]=self), scalar-forced slot ids.
template<int H, bool LAST>
__global__ __launch_bounds__(256) void k_fused(
    const int* __restrict__ cnt, const int* __restrict__ slots,
    const __half* __restrict__ xlh, const float* __restrict__ xr,
    const float* __restrict__ att, const float* __restrict__ bias,
    float* __restrict__ out)
{
    const int lane = threadIdx.x & 63;
    const int node = __builtin_amdgcn_readfirstlane(blockIdx.x * 4 + (threadIdx.x >> 6));
    if (node >= NN) return;
    const float xr_v = xr[(size_t)node*64 + lane];
    const float att_v = att[lane] * 1.44269504088896f;   // fold log2(e)
    const float bias_v = bias[lane];
    int deg = __builtin_amdgcn_readfirstlane(cnt[node]);
    deg = deg > CAP ? CAP : deg;
    const int* __restrict__ sp = slots + (size_t)node * CAP;   // sp[0] = self

    float den = 0.f, acc = 0.f;
    const int nchunk = (deg + 7) >> 3;

    for (int c = 0; c < nchunk; ++c){
        const int b0 = c*8;
        const int nv = deg - b0;           // valid edges in this chunk (>=1)
        int id[8]; float xv[8], q[8], e[8];
        #pragma unroll
        for (int j = 0; j < 8; ++j)
            id[j] = __builtin_amdgcn_readfirstlane((j < nv) ? sp[b0+j] : node);
        #pragma unroll
        for (int j = 0; j < 8; ++j) xv[j] = __half2float(xlh[(unsigned)(id[j]*64) + lane]);
        #pragma unroll
        for (int j = 0; j < 8; ++j) q[j] = edge_logit<H>(xv[j], xr_v, att_v);
        if (nv < 8){                        // tail chunk only: kill invalid edges
            #pragma unroll
            for (int j = 1; j < 8; ++j) if (j >= nv) q[j] = -16384.f;   // exp2 -> 0
        }
        #pragma unroll
        for (int j = 0; j < 8; ++j) e[j] = __builtin_amdgcn_exp2f(q[j]);
        #pragma unroll
        for (int j = 0; j < 8; ++j) acc = fmaf(e[j], xv[j], acc);
        den += ((e[0]+e[1]) + (e[2]+e[3])) + ((e[4]+e[5]) + (e[6]+e[7]));
    }

    float o = fmaf(acc, __builtin_amdgcn_rcpf(den), bias_v);
    if (!LAST) o = fmaxf(o, 0.f);
    const float nsum = head_reduce<1>(fabsf(o));
    o *= __builtin_amdgcn_rcpf(fmaxf(nsum, 1e-12f));
    if (LAST){
        const float qq = head_reduce<1>(o * o);
        o *= __builtin_amdgcn_rsqf(fmaxf(qq, 1e-24f));
        o = fmaxf(o, 0.f);
    }
    out[(size_t)node*64 + lane] = o;
}

// ---- fallback-path build (atomic, R8 style) ----
__global__ __launch_bounds__(256) void k_init(int* __restrict__ cnt, int* __restrict__ slots)
{
    const int i = blockIdx.x * 256 + threadIdx.x;
    if (i < NN){ cnt[i] = 1; slots[(size_t)i * CAP] = i; }
}
__global__ __launch_bounds__(256) void k_build(
    const int* __restrict__ ei, int* __restrict__ cnt, int* __restrict__ slots)
{
    const int stride = gridDim.x * 256;
    for (int e = blockIdx.x * 256 + threadIdx.x; e < EE; e += stride){
        const int s = ei[e], d = ei[e + EE];
        const int pos = atomicAdd(&cnt[d], 1);
        if (pos < CAP) slots[(size_t)d * CAP + pos] = s;
    }
}

extern "C" void kernel_launch(void* const* d_in, const int* in_sizes, int n_in,
                              void* d_out, int out_size, void* d_ws, size_t ws_size,
                              hipStream_t stream)
{
    const float* x0 = (const float*)d_in[0];
    const int* ei[3] = {(const int*)d_in[1], (const int*)d_in[2], (const int*)d_in[3]};
    const float *Wl[3], *bl[3], *Wr[3], *br[3], *att[3], *bias[3];
    for (int i = 0; i < 3; ++i){
        Wl[i]   = (const float*)d_in[4 + 6*i];
        bl[i]   = (const float*)d_in[5 + 6*i];
        Wr[i]   = (const float*)d_in[6 + 6*i];
        br[i]   = (const float*)d_in[7 + 6*i];
        att[i]  = (const float*)d_in[8 + 6*i];
        bias[i] = (const float*)d_in[9 + 6*i];
    }
    float* out = (float*)d_out;

    const size_t NN64 = (size_t)NN * 64;
    __half* xlh = (__half*)d_ws;                       // 12.8 MB
    float*  xr  = (float*)((char*)d_ws + NN64*2);      // 25.6 MB
    float*  xb  = out;                                 // inter-layer activation in d_out
    int* base = (int*)(xr + NN64);

    // bytes: xlh(2) + xr(4) per elem + buckets + tail
    const size_t fused_need = NN64*2 + NN64*4 + (3*(size_t)NN*(CAP+1) + 3*NBIN)*4;

    dim3 blk(256);
    const int ggrid = (NN + 63) / 64;
    const int ngrid = (NN + 3) / 4;
    const int igrid = (NN + 255) / 256;

    if (ws_size >= fused_need){
        // bucket arrays (3 layers)
        int* c0 = base;                 int* s0 = c0 + NN;
        int* c1 = s0 + (size_t)NN*CAP;  int* s1 = c1 + NN;
        int* c2 = s1 + (size_t)NN*CAP;  int* s2 = c2 + NN;
        int* tail = s2 + (size_t)NN*CAP;            // 3*NBIN ints
        // pairs: p0 in d_out (16.3 <= 25.6 MB, dead before fused0 writes xb);
        // p1/p2 alias xlh+xr (32.6 <= 38.4 MB, dead before gemm0 writes them)
        int2* p0 = (int2*)out;
        int2* p1 = (int2*)d_ws;
        int2* p2 = p1 + (size_t)NBIN*BINCAP;

        hipMemsetAsync(tail, 0, 3*NBIN*sizeof(int), stream);
        k_A<<<3*NCA, blk, 0, stream>>>(ei[0], ei[1], ei[2], p0, p1, p2, tail);
        k_B<<<3*NBIN, blk, 0, stream>>>(p0, p1, p2, tail, c0, s0, c1, s1, c2, s2);

        k_gemm<128><<<ggrid, blk, 0, stream>>>(x0, Wl[0], bl[0], Wr[0], br[0], xlh, xr);
        k_fused<4,false><<<ngrid, blk, 0, stream>>>(c0, s0, xlh, xr, att[0], bias[0], xb);
        k_gemm<64><<<ggrid, blk, 0, stream>>>(xb, Wl[1], bl[1], Wr[1], br[1], xlh, xr);
        k_fused<4,false><<<ngrid, blk, 0, stream>>>(c1, s1, xlh, xr, att[1], bias[1], xb);
        k_gemm<64><<<ggrid, blk, 0, stream>>>(xb, Wl[2], bl[2], Wr[2], br[2], xlh, xr);
        k_fused<1,true><<<ngrid, blk, 0, stream>>>(c2, s2, xlh, xr, att[2], bias[2], out);
    } else {
        // sequential fallback: one bucket set, atomic build
        int* cnt = base;
        int* slots = cnt + NN;

        k_init<<<igrid, blk, 0, stream>>>(cnt, slots);
        k_gemm<128><<<ggrid, blk, 0, stream>>>(x0, Wl[0], bl[0], Wr[0], br[0], xlh, xr);
        k_build<<<512, blk, 0, stream>>>(ei[0], cnt, slots);
        k_fused<4,false><<<ngrid, blk, 0, stream>>>(cnt, slots, xlh, xr, att[0], bias[0], xb);

        k_init<<<igrid, blk, 0, stream>>>(cnt, slots);
        k_gemm<64><<<ggrid, blk, 0, stream>>>(xb, Wl[1], bl[1], Wr[1], br[1], xlh, xr);
        k_build<<<512, blk, 0, stream>>>(ei[1], cnt, slots);
        k_fused<4,false><<<ngrid, blk, 0, stream>>>(cnt, slots, xlh, xr, att[1], bias[1], xb);

        k_init<<<igrid, blk, 0, stream>>>(cnt, slots);
        k_gemm<64><<<ggrid, blk, 0, stream>>>(xb, Wl[2], bl[2], Wr[2], br[2], xlh, xr);
        k_build<<<512, blk, 0, stream>>>(ei[2], cnt, slots);
        k_fused<1,true><<<ngrid, blk, 0, stream>>>(cnt, slots, xlh, xr, att[2], bias[2], out);
    }
}